// Round 8
// baseline (909.318 us; speedup 1.0000x reference)
//
#include <hip/hip_runtime.h>
#include <math.h>

#define NEGV -1e10f

typedef __bf16 bf16x8 __attribute__((ext_vector_type(8)));
typedef float f32x4 __attribute__((ext_vector_type(4)));
typedef unsigned short ushort;

__device__ __forceinline__ float fast_tanh(float x) {
    float e = __expf(2.0f * x);
    return fmaf(-2.f, __builtin_amdgcn_rcpf(e + 1.f), 1.f);
}
__device__ __forceinline__ float fast_sig(float x) {
    return __builtin_amdgcn_rcpf(1.f + __expf(-x));
}
__device__ __forceinline__ ushort f2bf(float x) {
    unsigned int b = __float_as_uint(x);
    b += 0x7fffu + ((b >> 16) & 1u);   // RNE
    return (ushort)(b >> 16);
}
// async 16B global -> LDS (dest = wave-uniform base + lane*16)
__device__ __forceinline__ void async16(void* l, const void* g) {
    __builtin_amdgcn_global_load_lds(
        (const __attribute__((address_space(1))) void*)g,
        (__attribute__((address_space(3))) void*)l,
        16, 0, 0);
}

// ---------------- fp32 -> bf16 cast (n % 8 == 0) ----------------
__global__ __launch_bounds__(256) void cast_bf16_kernel(
    const float* __restrict__ in, ushort* __restrict__ out, int n)
{
    int i = (blockIdx.x * 256 + threadIdx.x) * 8;
    if (i >= n) return;
    float4 a = *(const float4*)(in + i);
    float4 b = *(const float4*)(in + i + 4);
    uint4 o;
    o.x = (unsigned)f2bf(a.x) | ((unsigned)f2bf(a.y) << 16);
    o.y = (unsigned)f2bf(a.z) | ((unsigned)f2bf(a.w) << 16);
    o.z = (unsigned)f2bf(b.x) | ((unsigned)f2bf(b.y) << 16);
    o.w = (unsigned)f2bf(b.z) | ((unsigned)f2bf(b.w) << 16);
    *(uint4*)(out + i) = o;
}

// ---------------- dual fp32 -> bf16 cast (both n % 8 == 0) ----------------
__global__ __launch_bounds__(256) void cast2_bf16_kernel(
    const float* __restrict__ inA, const float* __restrict__ inB,
    ushort* __restrict__ outA, ushort* __restrict__ outB, int nA, int nB)
{
    int i = (blockIdx.x * 256 + threadIdx.x) * 8;
    const float* in;
    ushort* out;
    if (i < nA) { in = inA; out = outA; }
    else {
        i -= nA;
        if (i >= nB) return;
        in = inB; out = outB;
    }
    float4 a = *(const float4*)(in + i);
    float4 b = *(const float4*)(in + i + 4);
    uint4 o;
    o.x = (unsigned)f2bf(a.x) | ((unsigned)f2bf(a.y) << 16);
    o.y = (unsigned)f2bf(a.z) | ((unsigned)f2bf(a.w) << 16);
    o.z = (unsigned)f2bf(b.x) | ((unsigned)f2bf(b.y) << 16);
    o.w = (unsigned)f2bf(b.z) | ((unsigned)f2bf(b.w) << 16);
    *(uint4*)(out + i) = o;
}

// ---------------- bias concat: 8 vectors of 256 -> bias_all[4][512] ----------------
__global__ __launch_bounds__(256) void prepack_bias_kernel(
    const float* s0, const float* s1, const float* s2, const float* s3,
    const float* s4, const float* s5, const float* s6, const float* s7,
    float* __restrict__ dst)
{
    const float* srcs[8] = {s0, s1, s2, s3, s4, s5, s6, s7};
    dst[blockIdx.x * 256 + threadIdx.x] = srcs[blockIdx.x][threadIdx.x];
}

// ---------------- pad-cast A: in[M][140] f32 -> out[M][192] bf16 (zero pad) ----------------
__global__ __launch_bounds__(256) void pad_cast_a_kernel(
    const float* __restrict__ in, ushort* __restrict__ out, int M, int sk)
{
    int idx = blockIdx.x * 256 + threadIdx.x;       // row*24 + oct
    if (idx >= M * 24) return;
    int row = idx / 24, oct = idx - row * 24;
    int c0 = oct * 8;
    const float* src = in + (size_t)row * sk;
    ushort v[8];
    #pragma unroll
    for (int j = 0; j < 8; j++) {
        int c = c0 + j;
        v[j] = (c < 140) ? f2bf(src[c]) : (ushort)0;
    }
    *(uint4*)(out + (size_t)row * 192 + c0) = *(const uint4*)v;
}

// ---------------- pad-cast B: src rows -> dst[Nout][192] bf16 ----------------
__global__ __launch_bounds__(96) void pad_cast_b_kernel(
    const float* __restrict__ src, ushort* __restrict__ dst,
    int Nsrc, int srcld, int soff)
{
    int row = blockIdx.x;
    int t = threadIdx.x;            // cols 2t, 2t+1
    float a = 0.f, b = 0.f;
    if (row < Nsrc) {
        const float* s = src + (size_t)row * srcld + soff;
        if (2 * t < 140) a = s[2 * t];
        if (2 * t + 1 < 140) b = s[2 * t + 1];
    }
    ((unsigned*)(dst + (size_t)row * 192))[t] =
        (unsigned)f2bf(a) | ((unsigned)f2bf(b) << 16);
}

__global__ __launch_bounds__(256) void pad_bias_kernel(
    const float* __restrict__ in, float* __restrict__ out, int n)
{
    int i = threadIdx.x;
    out[i] = (i < n) ? in[i] : 0.f;
}

// ------------- pre-pack Whh (8 matrices [256][64]) into MFMA B-frag order -------------
__global__ __launch_bounds__(256) void prepack_whh_kernel(
    const float* W0, const float* W1, const float* W2, const float* W3,
    const float* W4, const float* W5, const float* W6, const float* W7,
    ushort* frag)
{
    const float* Ws[8] = {W0, W1, W2, W3, W4, W5, W6, W7};
    const float* W = Ws[blockIdx.x];
    ushort* out = frag + (size_t)blockIdx.x * 16384;
    for (int r = 0; r < 8; r++) {
        int fl = threadIdx.x + 256 * r;            // 0..2047
        int tile = fl >> 7;
        int chunk = (fl >> 6) & 1;
        int lane = fl & 63;
        int row = tile * 16 + (lane & 15);
        int kb = chunk * 32 + 8 * (lane >> 4);
        #pragma unroll
        for (int j = 0; j < 8; j++)
            out[(size_t)fl * 8 + j] = f2bf(W[row * 64 + kb + j]);
    }
}

// =============== device GEMM: C = A[.,K]bf16 @ B[.,K]bf16^T (+bias) ===============
// mode 1: fp32 store, cols < Nstore. mode 2: bf16 store, scan-perm layout
// (col = dir*256+g*64+u  ->  dir*256 + u*4 + g), ldc elements.
__device__ __forceinline__ void gemm_dev(
    const ushort* __restrict__ A, const ushort* __restrict__ B,
    const float* __restrict__ bias, void* __restrict__ C,
    int K, int ldc, int Nstore, int mode, int bm, int bn,
    ushort* ldsA, ushort* ldsB)
{
    const int tid = threadIdx.x;
    const int wv = tid >> 6, ln = tid & 63;
    const int r15 = ln & 15, r4 = ln >> 4;

    f32x4 acc[4][4] = {};

    for (int k0 = 0; k0 < K; k0 += 64) {
        #pragma unroll
        for (int c4 = 0; c4 < 4; c4++) {
            const int c = c4 * 4 + wv;
            const int s = c * 64 + ln;
            const int rt = s >> 3;
            const int ce = ((s & 7) ^ (rt & 7)) * 8;   // T2 swizzle (both sides)
            async16(&ldsA[c * 512], A + (size_t)(bm + rt) * K + k0 + ce);
            async16(&ldsB[c * 512], B + (size_t)(bn + rt) * K + k0 + ce);
        }
        __syncthreads();
        const int mr = (wv >> 1) * 64, nc = (wv & 1) * 64;
        #pragma unroll
        for (int kk = 0; kk < 2; kk++) {
            bf16x8 af[4], bfr[4];
            #pragma unroll
            for (int m = 0; m < 4; m++) {
                const int r = mr + m * 16 + r15;
                const int off = r * 128 + ((kk * 64 + r4 * 16) ^ ((r & 7) << 4));
                af[m] = *(const bf16x8*)((const char*)ldsA + off);
            }
            #pragma unroll
            for (int n = 0; n < 4; n++) {
                const int r = nc + n * 16 + r15;
                const int off = r * 128 + ((kk * 64 + r4 * 16) ^ ((r & 7) << 4));
                bfr[n] = *(const bf16x8*)((const char*)ldsB + off);
            }
            #pragma unroll
            for (int m = 0; m < 4; m++)
                #pragma unroll
                for (int n = 0; n < 4; n++)
                    acc[m][n] = __builtin_amdgcn_mfma_f32_16x16x32_bf16(
                        af[m], bfr[n], acc[m][n], 0, 0, 0);
        }
        __syncthreads();
    }
    const int mro = bm + (wv >> 1) * 64, nco = bn + (wv & 1) * 64;
    #pragma unroll
    for (int m = 0; m < 4; m++) {
        #pragma unroll
        for (int n = 0; n < 4; n++) {
            const int col = nco + n * 16 + r15;
            const float bs = bias ? bias[col] : 0.f;
            if (mode == 2) {
                const int cout = (col >> 8) * 256 + (col & 63) * 4 + ((col >> 6) & 3);
                #pragma unroll
                for (int r = 0; r < 4; r++) {
                    const int row = mro + m * 16 + r4 * 4 + r;
                    ((ushort*)C)[(size_t)row * ldc + cout] = f2bf(acc[m][n][r] + bs);
                }
            } else if (col < Nstore) {
                #pragma unroll
                for (int r = 0; r < 4; r++) {
                    const int row = mro + m * 16 + r4 * 4 + r;
                    ((float*)C)[(size_t)row * ldc + col] = acc[m][n][r] + bs;
                }
            }
        }
    }
}

// =============== device LSTM scan: one wave per (chain, dir) ===============
// proj bf16 [ch][T][dir*256 + u*4 + g]; wf register-resident; in-lane gates;
// gate-grouped MFMA consumption (4 live accs); depth-4 prefetch ring; no barrier.
// OBF=1: output bf16 (ushort), OBF=0: fp32.
#define GATE_GROUP(XR, T0, T1, T2, T3)                                              \
    {                                                                               \
        f32x4 u0 = z, u1 = z, u2 = z, u3 = z;                                       \
        u0 = __builtin_amdgcn_mfma_f32_16x16x32_bf16(a0, wf[T0][0], u0, 0, 0, 0);   \
        u1 = __builtin_amdgcn_mfma_f32_16x16x32_bf16(a0, wf[T1][0], u1, 0, 0, 0);   \
        u2 = __builtin_amdgcn_mfma_f32_16x16x32_bf16(a0, wf[T2][0], u2, 0, 0, 0);   \
        u3 = __builtin_amdgcn_mfma_f32_16x16x32_bf16(a0, wf[T3][0], u3, 0, 0, 0);   \
        u0 = __builtin_amdgcn_mfma_f32_16x16x32_bf16(a1, wf[T0][1], u0, 0, 0, 0);   \
        u1 = __builtin_amdgcn_mfma_f32_16x16x32_bf16(a1, wf[T1][1], u1, 0, 0, 0);   \
        u2 = __builtin_amdgcn_mfma_f32_16x16x32_bf16(a1, wf[T2][1], u2, 0, 0, 0);   \
        u3 = __builtin_amdgcn_mfma_f32_16x16x32_bf16(a1, wf[T3][1], u3, 0, 0, 0);   \
        XR = (q == 0) ? u0[0] : (q == 1) ? u1[0] : (q == 2) ? u2[0] : u3[0];        \
    }

template<int OBF>
__device__ __forceinline__ void scan_dev(
    const ushort* __restrict__ proj,
    const ushort* __restrict__ frag_f, const ushort* __restrict__ frag_b,
    const int* __restrict__ lengths, void* __restrict__ out,
    int T, int os, int ch, int dir, ushort* h2)
{
    const int l = threadIdx.x;
    const int q = l >> 4;
    const ushort* projc = proj + (size_t)ch * T * 512 + dir * 256;
    const ushort* frag = dir ? frag_b : frag_f;
    const int L = lengths[ch];

    bf16x8 wf[16][2];
    #pragma unroll
    for (int t16 = 0; t16 < 16; t16++)
        #pragma unroll
        for (int c = 0; c < 2; c++)
            wf[t16][c] = *(const bf16x8*)(frag + (((size_t)t16 * 2 + c) * 64 + l) * 8);

    h2[l] = 0;
    float cst = 0.f;
    const long od = dir ? -(long)os : (long)os;
    const size_t obase = (size_t)ch * T * os
                       + (size_t)(dir ? (L - 1) : 0) * os + dir * 64 + l;
    float* orow_f = (float*)out + obase;
    ushort* orow_h = (ushort*)out + obase;

    auto ld = [&](int s) -> uint2 {
        int tc = (s < L) ? s : (L - 1);
        int t = dir ? (L - 1 - tc) : tc;
        return *(const uint2*)(projc + (size_t)t * 512 + 4 * l);
    };
    uint2 P0 = ld(0), P1 = ld(1), P2 = ld(2), P3 = ld(3);
    const f32x4 z = {0.f, 0.f, 0.f, 0.f};

    for (int s = 0; s < L; s++) {
        const char* hb = (const char*)h2;
        bf16x8 a0 = *(const bf16x8*)(hb + q * 16);        // h[8q..8q+7]
        bf16x8 a1 = *(const bf16x8*)(hb + 64 + q * 16);   // h[32+8q..]
        float xi, xf, xg, xo;
        GATE_GROUP(xi, 0, 1, 2, 3)
        GATE_GROUP(xf, 4, 5, 6, 7)
        GATE_GROUP(xg, 8, 9, 10, 11)
        GATE_GROUP(xo, 12, 13, 14, 15)
        const float pi = __uint_as_float(P0.x << 16);
        const float pf = __uint_as_float(P0.x & 0xffff0000u);
        const float pg = __uint_as_float(P0.y << 16);
        const float po = __uint_as_float(P0.y & 0xffff0000u);
        const float iv = fast_sig(xi + pi);
        const float fv = fast_sig(xf + pf);
        const float gv = fast_tanh(xg + pg);
        const float ov = fast_sig(xo + po);
        cst = fmaf(fv, cst, iv * gv);
        const float hv = ov * fast_tanh(cst);
        const ushort hb16 = f2bf(hv);
        h2[l] = hb16;                     // same-wave in-order LDS (R7-verified)
        if (OBF) { *orow_h = hb16; orow_h += od; }
        else     { *orow_f = hv;   orow_f += od; }
        P0 = P1; P1 = P2; P2 = P3;
        P3 = ld(s + 4);
    }

    // zero-fill masked region t in [L, T)
    if (OBF) {
        ushort* ob = (ushort*)out + (size_t)ch * T * os + dir * 64;
        for (int idx = l; idx < (T - L) * 64; idx += 64) {
            int t = L + (idx >> 6);
            ob[(size_t)t * os + (idx & 63)] = 0;
        }
    } else {
        float* ob = (float*)out + (size_t)ch * T * os + dir * 64;
        for (int idx = l; idx < (T - L) * 64; idx += 64) {
            int t = L + (idx >> 6);
            ob[(size_t)t * os + (idx & 63)] = 0.f;
        }
    }
}

// ---------------- standalone MFMA GEMM ----------------
__global__ __launch_bounds__(256) void gemm_mfma_kernel(
    const ushort* __restrict__ A, const ushort* __restrict__ B,
    const float* __restrict__ bias, void* __restrict__ C,
    int K, int ldc, int Nstore, int mode)
{
    __shared__ __align__(16) ushort smem[16384];
    gemm_dev(A, B, bias, C, K, ldc, Nstore, mode,
             blockIdx.y * 128, blockIdx.x * 128, smem, smem + 8192);
}

// ---------------- fused: scanA blocks | scanB blocks | gemm blocks ----------------
template<int OBFA, int OBFB>
__global__ __launch_bounds__(256) void fused_kernel(
    int nsA, const ushort* projA, const ushort* fAf, const ushort* fAb,
    const int* lenA, void* outA, int TA, int osA,
    int nsB, const ushort* projB, const ushort* fBf, const ushort* fBb,
    const int* lenB, void* outB, int TB, int osB,
    int ngN, const ushort* gA, const ushort* gB, const float* gbias,
    void* gC, int gK, int gldc, int gNstore, int gmode)
{
    __shared__ __align__(16) ushort smem[16384];
    int bx = blockIdx.x;
    if (bx < nsA) {
        if (threadIdx.x >= 64) return;
        scan_dev<OBFA>(projA, fAf, fAb, lenA, outA, TA, osA, bx >> 1, bx & 1, smem);
        return;
    }
    bx -= nsA;
    if (bx < nsB) {
        if (threadIdx.x >= 64) return;
        scan_dev<OBFB>(projB, fBf, fBb, lenB, outB, TB, osB, bx >> 1, bx & 1, smem);
        return;
    }
    bx -= nsB;
    gemm_dev(gA, gB, gbias, gC, gK, gldc, gNstore, gmode,
             (bx / ngN) * 128, (bx % ngN) * 128, smem, smem + 8192);
}

// ---------------- SIMT GEMM (small tail): C = A @ B^T (+bias) ----------------
__global__ __launch_bounds__(256) void gemm_bias_kernel(
    const float* __restrict__ A, const float* __restrict__ B,
    const float* __restrict__ bias, float* __restrict__ C,
    int M, int N, int K, int lda, int ldb, int ldc)
{
    __shared__ float As[16][68];
    __shared__ float Bs[16][68];
    const int tid = threadIdx.x;
    const int bm = blockIdx.y * 64;
    const int bn = blockIdx.x * 64;
    const int tx = tid & 15;
    const int ty = tid >> 4;
    const int lm = tid & 63;
    const int lk = (tid >> 6) << 2;
    float acc[4][4] = {};
    const int arow = bm + lm;
    const int brow = bn + lm;

    for (int k0 = 0; k0 < K; k0 += 16) {
        int k = k0 + lk;
        float4 av = make_float4(0.f, 0.f, 0.f, 0.f);
        float4 bv = make_float4(0.f, 0.f, 0.f, 0.f);
        if (arow < M) {
            if (k + 4 <= K) av = *(const float4*)(A + (size_t)arow * lda + k);
            else { float* p = (float*)&av;
                for (int i = 0; i < 4; i++) if (k + i < K) p[i] = A[(size_t)arow * lda + k + i]; }
        }
        if (brow < N) {
            if (k + 4 <= K) bv = *(const float4*)(B + (size_t)brow * ldb + k);
            else { float* p = (float*)&bv;
                for (int i = 0; i < 4; i++) if (k + i < K) p[i] = B[(size_t)brow * ldb + k + i]; }
        }
        As[lk + 0][lm] = av.x; As[lk + 1][lm] = av.y; As[lk + 2][lm] = av.z; As[lk + 3][lm] = av.w;
        Bs[lk + 0][lm] = bv.x; Bs[lk + 1][lm] = bv.y; Bs[lk + 2][lm] = bv.z; Bs[lk + 3][lm] = bv.w;
        __syncthreads();
        #pragma unroll
        for (int kk = 0; kk < 16; kk++) {
            float a[4], bb[4];
            #pragma unroll
            for (int i = 0; i < 4; i++) a[i] = As[kk][ty * 4 + i];
            #pragma unroll
            for (int j = 0; j < 4; j++) bb[j] = Bs[kk][tx * 4 + j];
            #pragma unroll
            for (int i = 0; i < 4; i++)
                #pragma unroll
                for (int j = 0; j < 4; j++)
                    acc[i][j] = fmaf(a[i], bb[j], acc[i][j]);
        }
        __syncthreads();
    }
    #pragma unroll
    for (int i = 0; i < 4; i++) {
        int row = bm + ty * 4 + i;
        if (row >= M) continue;
        #pragma unroll
        for (int j = 0; j < 4; j++) {
            int col = bn + tx * 4 + j;
            if (col < N) C[(size_t)row * ldc + col] = acc[i][j] + (bias ? bias[col] : 0.f);
        }
    }
}

// ---------------- one-hot knowledge into wenc_n cols 128..139 ----------------
__global__ __launch_bounds__(256) void onehot_kernel(
    const int* __restrict__ knowledge, float* __restrict__ wenc_n)
{
    int idx = blockIdx.x * 256 + threadIdx.x;
    if (idx >= 96 * 512) return;
    int kn = knowledge[idx];
    float* row = wenc_n + (size_t)idx * 140 + 128;
    #pragma unroll
    for (int q = 0; q < 12; q++) row[q] = (q == kn) ? 1.f : 0.f;
}

// ---------------- header: pick last valid step + one-hot ----------------
__global__ __launch_bounds__(256) void build_hs_kernel(
    const float* __restrict__ h1_head, const int* __restrict__ l_hpu,
    const int* __restrict__ knowledge_header, float* __restrict__ wenc_hs)
{
    int b = blockIdx.x, u = blockIdx.y;
    int g = b * 16 + u;
    int tid = threadIdx.x;
    int L = l_hpu[g];
    if (tid < 128) {
        wenc_hs[(size_t)g * 132 + tid] = h1_head[((size_t)g * 8 + (L - 1)) * 128 + tid];
    } else if (tid < 132) {
        int kh = knowledge_header[g];
        wenc_hs[(size_t)g * 132 + tid] = ((tid - 128) == kh) ? 1.f : 0.f;
    }
}

__global__ __launch_bounds__(256) void build_hsob_kernel(
    const float* __restrict__ wenc_hs, const int* __restrict__ wc,
    const int* __restrict__ wn, float* __restrict__ hs_ob)
{
    int b = blockIdx.x, w = blockIdx.y;
    int tid = threadIdx.x;
    int col = (w < wn[b]) ? wc[b * 4 + w] : 0;
    if (tid < 132)
        hs_ob[((size_t)b * 4 + w)* 132 + tid] = wenc_hs[((size_t)b * 16 + col) * 132 + tid];
}

// ---------------- attention scores + softmax + context (per (b,w)) ----------------
__global__ __launch_bounds__(256) void att_softmax_cn_kernel(
    const float* __restrict__ attx, const float* __restrict__ hs_ob,
    const float* __restrict__ wenc_n, const int* __restrict__ l_n,
    float* __restrict__ c_n)
{
    int b = blockIdx.x, w = blockIdx.y;
    int tid = threadIdx.x;
    int L = l_n[b];
    __shared__ float q[132];
    __shared__ float sc[512];
    __shared__ float red[256];
    if (tid < 132) q[tid] = hs_ob[((size_t)b * 4 + w) * 132 + tid];
    __syncthreads();
    for (int t = tid; t < 512; t += 256) {
        float s = -1e30f;
        if (t < L) {
            const float* ax = attx + ((size_t)b * 512 + t) * 132;
            float s0 = 0.f, s1 = 0.f, s2 = 0.f, s3 = 0.f;
            #pragma unroll
            for (int d = 0; d < 132; d += 4) {
                s0 = fmaf(ax[d + 0], q[d + 0], s0);
                s1 = fmaf(ax[d + 1], q[d + 1], s1);
                s2 = fmaf(ax[d + 2], q[d + 2], s2);
                s3 = fmaf(ax[d + 3], q[d + 3], s3);
            }
            s = (s0 + s1) + (s2 + s3);
        }
        sc[t] = s;
    }
    __syncthreads();
    red[tid] = fmaxf(sc[tid], sc[tid + 256]);
    __syncthreads();
    for (int off = 128; off > 0; off >>= 1) {
        if (tid < off) red[tid] = fmaxf(red[tid], red[tid + off]);
        __syncthreads();
    }
    float m = red[0];
    __syncthreads();
    float ps = 0.f;
    for (int t = tid; t < 512; t += 256) {
        float e = (t < L) ? __expf(sc[t] - m) : 0.f;
        sc[t] = e;
        ps += e;
    }
    red[tid] = ps;
    __syncthreads();
    for (int off = 128; off > 0; off >>= 1) {
        if (tid < off) red[tid] += red[tid + off];
        __syncthreads();
    }
    float inv = 1.f / red[0];
    if (tid < 140) {
        float acc = 0.f;
        for (int t = 0; t < L; t++)
            acc = fmaf(sc[t], wenc_n[((size_t)b * 512 + t) * 140 + tid], acc);
        c_n[((size_t)b * 4 + w) * 140 + tid] = acc * inv;
    }
}

// ---------------- vec = [c_n@Wc.T+b | hs_ob@Whs.T+b | Wop[:,op]+b] ----------------
__global__ __launch_bounds__(384) void build_vec_kernel(
    const float* __restrict__ c_n, const float* __restrict__ hs_ob,
    const float* __restrict__ Wc_w, const float* __restrict__ Wc_b,
    const float* __restrict__ Whs_w, const float* __restrict__ Whs_b,
    const float* __restrict__ Wop_w, const float* __restrict__ Wop_b,
    const int* __restrict__ wn, const int* __restrict__ wo,
    float* __restrict__ vec)
{
    int b = blockIdx.x, w = blockIdx.y;
    int j = threadIdx.x;
    __shared__ float cn[140];
    __shared__ float hb[132];
    if (j < 140) cn[j] = c_n[((size_t)b * 4 + w) * 140 + j];
    else if (j < 272) hb[j - 140] = hs_ob[((size_t)b * 4 + w) * 132 + (j - 140)];
    __syncthreads();
    float acc;
    if (j < 128) {
        acc = Wc_b[j];
        const float* r = Wc_w + (size_t)j * 140;
        for (int d = 0; d < 140; d++) acc = fmaf(r[d], cn[d], acc);
    } else if (j < 256) {
        int jj = j - 128;
        acc = Whs_b[jj];
        const float* r = Whs_w + (size_t)jj * 132;
        for (int d = 0; d < 132; d++) acc = fmaf(r[d], hb[d], acc);
    } else {
        int jj = j - 256;
        int op = (w < wn[b]) ? wo[b * 4 + w] : 0;
        acc = Wop_b[jj] + Wop_w[jj * 4 + op];
    }
    vec[((size_t)b * 4 + w) * 384 + j] = acc;
}

// ---------------- final: out[b,w,t,:] = tanh(vpart+npart)@out2.T + b, masked ----------------
__global__ __launch_bounds__(256) void final_kernel(
    const float* __restrict__ vpart, const float* __restrict__ npart,
    const float* __restrict__ out2_w, const float* __restrict__ out2_b,
    const int* __restrict__ l_n, float* __restrict__ out)
{
    int b = blockIdx.y;
    int tid = threadIdx.x;
    int t = blockIdx.x * 256 + tid;
    __shared__ float vp[512];
    __shared__ float w2[256];
    w2[tid] = out2_w[tid];
    for (int i = tid; i < 512; i += 256) vp[i] = vpart[(size_t)b * 512 + i];
    __syncthreads();
    int L = l_n[b];
    float s[4][2];
    if (t < L) {
        float b0 = out2_b[0], b1 = out2_b[1];
        #pragma unroll
        for (int w = 0; w < 4; w++) { s[w][0] = b0; s[w][1] = b1; }
        const float4* np4 = (const float4*)(npart + ((size_t)b * 512 + t) * 128);
        for (int h4 = 0; h4 < 32; h4++) {
            float4 n = np4[h4];
            const float* nf = (const float*)&n;
            #pragma unroll
            for (int e = 0; e < 4; e++) {
                int h = h4 * 4 + e;
                float nv = nf[e];
                float w0 = w2[h], w1 = w2[128 + h];
                #pragma unroll
                for (int w = 0; w < 4; w++) {
                    float z = fast_tanh(vp[w * 128 + h] + nv);
                    s[w][0] = fmaf(z, w0, s[w][0]);
                    s[w][1] = fmaf(z, w1, s[w][1]);
                }
            }
        }
    } else {
        #pragma unroll
        for (int w = 0; w < 4; w++) { s[w][0] = NEGV; s[w][1] = NEGV; }
    }
    #pragma unroll
    for (int w = 0; w < 4; w++) {
        size_t o = (((size_t)b * 4 + w) * 512 + t) * 2;
        out[o + 0] = s[w][0];
        out[o + 1] = s[w][1];
    }
}

// ---------------------------------------------------------------------------
extern "C" void kernel_launch(void* const* d_in, const int* in_sizes, int n_in,
                              void* d_out, int out_size, void* d_ws, size_t ws_size,
                              hipStream_t stream)
{
    const float* wemb_n   = (const float*)d_in[0];
    const float* wemb_hpu = (const float*)d_in[1];
    const float* Wih_n0f = (const float*)d_in[2];
    const float* Whh_n0f = (const float*)d_in[3];
    const float* b_n0f   = (const float*)d_in[4];
    const float* Wih_n0b = (const float*)d_in[5];
    const float* Whh_n0b = (const float*)d_in[6];
    const float* b_n0b   = (const float*)d_in[7];
    const float* Wih_n1f = (const float*)d_in[8];
    const float* Whh_n1f = (const float*)d_in[9];
    const float* b_n1f   = (const float*)d_in[10];
    const float* Wih_n1b = (const float*)d_in[11];
    const float* Whh_n1b = (const float*)d_in[12];
    const float* b_n1b   = (const float*)d_in[13];
    const float* Wih_h0f = (const float*)d_in[14];
    const float* Whh_h0f = (const float*)d_in[15];
    const float* b_h0f   = (const float*)d_in[16];
    const float* Wih_h0b = (const float*)d_in[17];
    const float* Whh_h0b = (const float*)d_in[18];
    const float* b_h0b   = (const float*)d_in[19];
    const float* Wih_h1f = (const float*)d_in[20];
    const float* Whh_h1f = (const float*)d_in[21];
    const float* b_h1f   = (const float*)d_in[22];
    const float* Wih_h1b = (const float*)d_in[23];
    const float* Whh_h1b = (const float*)d_in[24];
    const float* b_h1b   = (const float*)d_in[25];
    const float* Watt_w  = (const float*)d_in[26];
    const float* Watt_b  = (const float*)d_in[27];
    const float* Wc_w    = (const float*)d_in[28];
    const float* Wc_b    = (const float*)d_in[29];
    const float* Whs_w   = (const float*)d_in[30];
    const float* Whs_b   = (const float*)d_in[31];
    const float* Wop_w   = (const float*)d_in[32];
    const float* Wop_b   = (const float*)d_in[33];
    const float* out1_w  = (const float*)d_in[34];
    const float* out1_b  = (const float*)d_in[35];
    const float* out2_w  = (const float*)d_in[36];
    const float* out2_b  = (const float*)d_in[37];
    const int* l_n   = (const int*)d_in[38];
    const int* l_hpu = (const int*)d_in[39];
    const int* wc    = (const int*)d_in[40];
    const int* wn    = (const int*)d_in[41];
    const int* wo    = (const int*)d_in[42];
    const int* knowledge        = (const int*)d_in[43];
    const int* knowledge_header = (const int*)d_in[44];

    float* ws = (float*)d_ws;
    // ---- workspace map (float offsets; lifetimes annotated) ----
    ushort* proj_q  = (ushort*)(ws + 0);          // [0,12582912)  49152x512 bf16
    ushort* proj_h  = (ushort*)(ws + 12582912);   // [12582912,15728640) 12288x512 bf16
    ushort* AbfH0   = (ushort*)(ws + 15728640);   // [15728640,18874368) wemb_hpu bf16 (dead after HG0)
    ushort* A_pad   = (ushort*)(ws + 15728640);   // reuse after HG0: [49152][192] -> [15728640,20447232)
    ushort* Bp_att  = (ushort*)(ws + 20447232);   // [20447232,20471808)
    ushort* Bp_out  = (ushort*)(ws + 20471808);   // [20471808,20484096)
    float*  bias_pad = ws + 20484096;             // [20484096,20484352)
    ushort* h_h0_bf = (ushort*)(ws + 22057216);   // [22057216,22843648) 12288x128 bf16
    ushort* WbfQ0   = (ushort*)(ws + 22843648);   // [22843648,22974720) 512x512
    ushort* WbfH0   = (ushort*)(ws + 22974720);   // [22974720,23105792)
    ushort* WbfQ1   = (ushort*)(ws + 23105792);   // [23105792,23138560) 512x128
    ushort* WbfH1   = (ushort*)(ws + 23138560);   // [23138560,23171328)
    ushort* wfrag   = (ushort*)(ws + 23171328);   // [23171328,23236864) 8x16384
    float*  bias_all = ws + 23236864;             // [23236864,23238912) [4][512]
    ushort* AbfQ0   = (ushort*)(ws + 25165824);   // [25165824,38338560) wemb_n bf16 (dead after QG0)
    float*  h1_head = ws + 26738688;              // [26738688,28311552) (after AbfQ0 dead)
    ushort* wenc0_bf = (ushort*)(ws + 31457280);  // [31457280,34603008) 49152x128 bf16 (after AbfQ0 dead)
    float*  wenc_n  = ws + 31457280;              // [31457280,38338560) (after wenc0_bf consumed)
    float*  attx    = ws + 0;                     // reuse proj_q after QS1
    float*  npart   = ws + 6488064;               // [6488064,12779520) after scans
    float*  wenc_hs = ws + 38338560;              // [38338560,38541312)
    float*  hs_ob   = ws + 38541312;
    float*  c_n     = ws + 38592000;
    float*  vec     = ws + 38645760;
    float*  vpart   = ws + 38793216;              // ends 38842368
    float*  outp    = (float*)d_out;

    dim3 blk(256);
    auto cast = [&](const float* in, ushort* out, int n) {
        cast_bf16_kernel<<<dim3((n / 8 + 255) / 256), blk, 0, stream>>>(in, out, n);
    };
    auto cast2 = [&](const float* a, const float* b, ushort* oa, ushort* ob, int na, int nb) {
        cast2_bf16_kernel<<<dim3(((na + nb) / 8 + 255) / 256), blk, 0, stream>>>(a, b, oa, ob, na, nb);
    };

    // ---- phase 1: packs + weight casts (all independent) ----
    prepack_whh_kernel<<<dim3(8), blk, 0, stream>>>(
        Whh_n0f, Whh_n0b, Whh_n1f, Whh_n1b, Whh_h0f, Whh_h0b, Whh_h1f, Whh_h1b, wfrag);
    prepack_bias_kernel<<<dim3(8), blk, 0, stream>>>(
        b_n0f, b_n0b, b_n1f, b_n1b, b_h0f, b_h0b, b_h1f, b_h1b, bias_all);
    pad_cast_b_kernel<<<dim3(256), dim3(96), 0, stream>>>(Watt_w, Bp_att, 132, 140, 0);
    pad_bias_kernel<<<dim3(1), blk, 0, stream>>>(Watt_b, bias_pad, 132);
    pad_cast_b_kernel<<<dim3(128), dim3(96), 0, stream>>>(out1_w, Bp_out, 128, 524, 384);
    cast(wemb_n, AbfQ0, 96 * 512 * 512);
    cast2(Wih_n0f, Wih_n0b, WbfQ0, WbfQ0 + 256 * 512, 256 * 512, 256 * 512);
    cast(wemb_hpu, AbfH0, 1536 * 8 * 512);
    cast2(Wih_h0f, Wih_h0b, WbfH0, WbfH0 + 256 * 512, 256 * 512, 256 * 512);
    cast2(Wih_n1f, Wih_n1b, WbfQ1, WbfQ1 + 256 * 128, 256 * 128, 256 * 128);
    cast2(Wih_h1f, Wih_h1b, WbfH1, WbfH1 + 256 * 128, 256 * 128, 256 * 128);

    // ---- QG0: question layer-0 input projection ----
    gemm_mfma_kernel<<<dim3(4, 384), blk, 0, stream>>>(
        AbfQ0, WbfQ0, bias_all + 0 * 512, proj_q, 512, 512, 512, 2);

    // ---- fused: QS0 (192 scans) || HG0 (384 gemm blocks) ----
    fused_kernel<1, 0><<<dim3(192 + 384), blk, 0, stream>>>(
        192, proj_q, wfrag + 0 * 16384, wfrag + 1 * 16384, l_n, wenc0_bf, 512, 128,
        0, proj_q, wfrag, wfrag, l_n, wenc0_bf, 1, 1,
        4, AbfH0, WbfH0, bias_all + 2 * 512, proj_h, 512, 512, 512, 2);

    // ---- fused: HS0 (3072 scans) || QG1 (1536 gemm blocks) ----
    fused_kernel<1, 0><<<dim3(3072 + 1536), blk, 0, stream>>>(
        3072, proj_h, wfrag + 4 * 16384, wfrag + 5 * 16384, l_hpu, h_h0_bf, 8, 128,
        0, proj_q, wfrag, wfrag, l_n, wenc0_bf, 1, 1,
        4, wenc0_bf, WbfQ1, bias_all + 1 * 512, proj_q, 128, 512, 512, 2);

    // ---- HG1: header layer-1 projection ----
    gemm_mfma_kernel<<<dim3(4, 96), blk, 0, stream>>>(
        h_h0_bf, WbfH1, bias_all + 3 * 512, proj_h, 128, 512, 512, 2);

    // ---- fused: QS1 (192 scans, fp32 out) || HS1 (3072 scans, fp32 out) ----
    fused_kernel<0, 0><<<dim3(192 + 3072), blk, 0, stream>>>(
        192, proj_q, wfrag + 2 * 16384, wfrag + 3 * 16384, l_n, wenc_n, 512, 140,
        3072, proj_h, wfrag + 6 * 16384, wfrag + 7 * 16384, l_hpu, h1_head, 8, 128,
        1, proj_q, wfrag, bias_all, proj_q, 64, 512, 0, 1);

    // ---- tail ----
    onehot_kernel<<<dim3(192), blk, 0, stream>>>(knowledge, wenc_n);
    build_hs_kernel<<<dim3(96, 16), blk, 0, stream>>>(h1_head, l_hpu, knowledge_header, wenc_hs);
    build_hsob_kernel<<<dim3(96, 4), blk, 0, stream>>>(wenc_hs, wc, wn, hs_ob);
    pad_cast_a_kernel<<<dim3((49152 * 24 + 255) / 256), blk, 0, stream>>>(wenc_n, A_pad, 49152, 140);
    gemm_mfma_kernel<<<dim3(2, 384), blk, 0, stream>>>(
        A_pad, Bp_att, bias_pad, attx, 192, 132, 132, 1);
    att_softmax_cn_kernel<<<dim3(96, 4), blk, 0, stream>>>(attx, hs_ob, wenc_n, l_n, c_n);
    build_vec_kernel<<<dim3(96, 4), dim3(384), 0, stream>>>(c_n, hs_ob, Wc_w, Wc_b,
                                                            Whs_w, Whs_b, Wop_w, Wop_b,
                                                            wn, wo, vec);
    gemm_bias_kernel<<<dim3(2, 6), blk, 0, stream>>>(vec, out1_w, out1_b, vpart,
                                                     384, 128, 384, 384, 524, 128);
    gemm_mfma_kernel<<<dim3(1, 384), blk, 0, stream>>>(
        A_pad, Bp_out, nullptr, npart, 192, 128, 128, 1);
    final_kernel<<<dim3(2, 96), blk, 0, stream>>>(vpart, npart, out2_w, out2_b, l_n, outp);
}